// Round 7
// baseline (397.596 us; speedup 1.0000x reference)
//
#include <hip/hip_runtime.h>
#include <math.h>

// Problem constants (Physics_Attention_Irregular_Mesh)
#define BQ   4
#define NTOK 16384
#define DIMM 256
#define HH   8
#define DDIM 64
#define SSL  64
#define INNERD 512
#define BN_TOK (BQ*NTOK)   // 65536

typedef __attribute__((ext_vector_type(8))) short short8;   // 8 bf16 (4 VGPRs)
typedef __attribute__((ext_vector_type(4))) float f32x4;    // 4 fp32 acc

// bf16 <-> f32 helpers (RNE)
__device__ inline float bf2f(unsigned short u) {
    union { float f; unsigned int i; } v; v.i = ((unsigned int)u) << 16; return v.f;
}
__device__ inline unsigned short f2bf(float f) {
    union { float f; unsigned int i; } v; v.f = f;
    unsigned int r = v.i + 0x7FFFu + ((v.i >> 16) & 1u);
    return (unsigned short)(r >> 16);
}

// async global->LDS, 16 B per lane (wave-uniform LDS base + lane*16)
__device__ __forceinline__ void gl_lds16(const void* g, void* l) {
    __builtin_amdgcn_global_load_lds(
        (const __attribute__((address_space(1))) unsigned int*)g,
        (__attribute__((address_space(3))) unsigned int*)l, 16, 0, 0);
}

#define WAIT_VM(N) asm volatile("s_waitcnt vmcnt(" #N ")" ::: "memory")
#define WAIT_LGKM0() asm volatile("s_waitcnt lgkmcnt(0)" ::: "memory")

// ---------------------------------------------------------------------------
// K0: merged weights (bf16 out).
// ---------------------------------------------------------------------------
__global__ void k_prep(const float* __restrict__ Wx, const float* __restrict__ bx,
                       const float* __restrict__ Wfx, const float* __restrict__ bfx,
                       const float* __restrict__ Wslice, const float* __restrict__ bslice,
                       unsigned short* __restrict__ Wcatb, float* __restrict__ bcat)
{
    int row = blockIdx.x;   // 0..1023
    int t = threadIdx.x;    // 64
    if (row < 512) {
        for (int c = t; c < 256; c += 64) Wcatb[row*256 + c] = f2bf(Wfx[row*256 + c]);
        if (t == 0) bcat[row] = bfx[row];
    } else {
        int r = row - 512, h = r >> 6, s = r & 63;
        for (int c = t; c < 256; c += 64) {
            float acc = 0.f;
            for (int d = 0; d < 64; ++d)
                acc += Wslice[s*64 + d] * Wx[(h*64 + d)*256 + c];
            Wcatb[row*256 + c] = f2bf(acc);
        }
        if (t == 0) {
            float acc = bslice[s];
            for (int d = 0; d < 64; ++d) acc += Wslice[s*64 + d] * bx[h*64 + d];
            bcat[row] = acc;
        }
    }
}

// x (fp32) -> xb (bf16), 8 elems/thread
__global__ void k_xcast(const float* __restrict__ x, unsigned short* __restrict__ xb)
{
    size_t i = ((size_t)blockIdx.x*256 + threadIdx.x)*8;
    float4 a = *(const float4*)(x + i);
    float4 b = *(const float4*)(x + i + 4);
    *(ushort4*)(xb + i)     = make_ushort4(f2bf(a.x), f2bf(a.y), f2bf(a.z), f2bf(a.w));
    *(ushort4*)(xb + i + 4) = make_ushort4(f2bf(b.x), f2bf(b.y), f2bf(b.z), f2bf(b.w));
}

// ---------------------------------------------------------------------------
// K1: MFMA GEMM (LOGITS ONLY) C[65536 x 512] = xb @ Wcatb[512:]^T + bcat[512:],
// fused per-head softmax epilogue -> wbuf[token][h*64+s].
// fx half removed: fx is recomputed inside k_tok (saves the 128 MB fx_t
// HBM round-trip). Per-block code identical to the verified R6 version.
// ---------------------------------------------------------------------------
__global__ __launch_bounds__(256) void k_gemm1(
    const unsigned short* __restrict__ Xb, const unsigned short* __restrict__ Wb,
    const float* __restrict__ bias, const float* __restrict__ temperature,
    unsigned short* __restrict__ wbuf)
{
    __shared__ unsigned short As[2][128*32];
    __shared__ unsigned short Bs[2][128*32];
    int bid = blockIdx.x;             // 2048
    int xcd = bid & 7;
    int inner = bid >> 3;             // 0..255
    int rt = xcd*64 + (inner >> 2);   // 0..511
    int ct = inner & 3;               // 0..3
    int m0 = rt*128, n0 = ct*128;     // n0: logit col base (0..383)
    int tid = threadIdx.x;
    int lane = tid & 63, w = tid >> 6;
    int wr = w >> 1, wc = w & 1;
    int lr = lane & 15, lq = lane >> 4;
    int lqs = lq ^ ((lr >> 1) & 3);   // swizzled read slot

    f32x4 acc[4][4];
#pragma unroll
    for (int i = 0; i < 4; i++)
#pragma unroll
        for (int j = 0; j < 4; j++) acc[i][j] = (f32x4)(0.f);

    int r0 = tid >> 2;
    int kswz = (((tid & 3) ^ ((tid >> 3) & 3))) * 8;   // pre-swizzled source slot

    auto stage = [&](int buf, int k0) {
        gl_lds16(Xb + (size_t)(m0 + r0)*256 + k0 + kswz,          &As[buf][(size_t)tid*8]);
        gl_lds16(Xb + (size_t)(m0 + 64 + r0)*256 + k0 + kswz,     &As[buf][(size_t)(tid+256)*8]);
        gl_lds16(Wb + (size_t)(512 + n0 + r0)*256 + k0 + kswz,    &Bs[buf][(size_t)tid*8]);
        gl_lds16(Wb + (size_t)(512 + n0 + 64 + r0)*256 + k0 + kswz, &Bs[buf][(size_t)(tid+256)*8]);
    };

    stage(0, 0);
    stage(1, 32);      // 8 vmem ops in flight per wave
    int cur = 0;
#pragma unroll
    for (int t = 0; t < 8; ++t) {
        if (t < 7) { WAIT_VM(4); } else { WAIT_VM(0); }
        __builtin_amdgcn_s_barrier();        // buf[cur] ready for all waves
        short8 af[4], bf[4];
#pragma unroll
        for (int i = 0; i < 4; i++) {
            af[i] = *(const short8*)&As[cur][(wr*64 + i*16 + lr)*32 + lqs*8];
            bf[i] = *(const short8*)&Bs[cur][(wc*64 + i*16 + lr)*32 + lqs*8];
        }
        WAIT_LGKM0();
        __builtin_amdgcn_sched_barrier(0);
        __builtin_amdgcn_s_barrier();        // all waves done reading buf[cur]
        if (t < 6) stage(cur, (t + 2) * 32); // overwrite cur for iter t+2
#pragma unroll
        for (int i = 0; i < 4; i++)
#pragma unroll
            for (int j = 0; j < 4; j++)
                acc[i][j] = __builtin_amdgcn_mfma_f32_16x16x32_bf16(af[i], bf[j], acc[i][j], 0, 0, 0);
        cur ^= 1;
    }

    float bv[4];
#pragma unroll
    for (int j = 0; j < 4; j++) bv[j] = bias[512 + n0 + wc*64 + j*16 + lr];

    // per-row softmax over this head's 64 cols
    int h = (n0 + wc*64) >> 6;
    float it = 1.f / fmaxf(temperature[h], 1e-4f);
    int colbase = n0 + wc*64;
#pragma unroll
    for (int i = 0; i < 4; i++) {
        int tokbase = m0 + wr*64 + i*16 + lq*4;
#pragma unroll
        for (int r = 0; r < 4; r++) {
            float v[4];
#pragma unroll
            for (int j = 0; j < 4; j++) v[j] = (acc[i][j][r] + bv[j]) * it;
            float mx = fmaxf(fmaxf(v[0], v[1]), fmaxf(v[2], v[3]));
            mx = fmaxf(mx, __shfl_xor(mx, 1));
            mx = fmaxf(mx, __shfl_xor(mx, 2));
            mx = fmaxf(mx, __shfl_xor(mx, 4));
            mx = fmaxf(mx, __shfl_xor(mx, 8));
            float e[4], sm = 0.f;
#pragma unroll
            for (int j = 0; j < 4; j++) { e[j] = __expf(v[j] - mx); sm += e[j]; }
            sm += __shfl_xor(sm, 1);
            sm += __shfl_xor(sm, 2);
            sm += __shfl_xor(sm, 4);
            sm += __shfl_xor(sm, 8);
            float inv = 1.f / sm;
            size_t rowoff = (size_t)(tokbase + r)*512 + colbase + lr;
#pragma unroll
            for (int j = 0; j < 4; j++)
                wbuf[rowoff + j*16] = f2bf(e[j] * inv);
        }
    }
}

// ---------------------------------------------------------------------------
// K2: fused fx-compute + tok-reduction. Per (chunk of 128 toks, b, h):
//   phase 1: fx[128 tok][64 d] = xb @ Wfx_h^T via MFMA (same staging/fragment
//            /K-order as the old gemm1 fx half -> bit-identical bf16 fx).
//   phase 2: acc -> LDS FX[d][tok] (16B-slot XOR swizzle, both sides).
//   phase 3: reduce over toks: tok[s][d] += w^T fx, norm from af registers.
// Eliminates the 128 MB fx_t HBM round-trip. Wfx_h tile (32 KB) is L2-hot;
// xb chunk is L3-resident (fetched 8x across heads, absorbed).
// ---------------------------------------------------------------------------
__global__ __launch_bounds__(256) void k_tok(
    const unsigned short* __restrict__ Xb, const unsigned short* __restrict__ Wcatb,
    const float* __restrict__ bcat, const unsigned short* __restrict__ wbuf,
    float* __restrict__ tok_acc, float* __restrict__ norm_acc)
{
    __shared__ unsigned short As[128*32];   // xb K-tile
    __shared__ unsigned short Bs[64*32];    // Wfx_h K-tile
    __shared__ unsigned short FX[64*128];   // [d][tok], slot-swizzled
    __shared__ unsigned short WL[128*64];   // [tok][s], token-major
    int chunk = blockIdx.x;   // 0..127 (within batch)
    int bh = blockIdx.y;      // 0..31
    int b = bh >> 3, h = bh & 7;
    size_t grow = (size_t)b*NTOK + chunk*128;   // global token row
    int tid = threadIdx.x;
    int lane = tid & 63, w = tid >> 6;
    int lr = lane & 15, lq = lane >> 4;
    int lqs = lq ^ ((lr >> 1) & 3);

    // stage w-tile upfront (completes under phase-1's barriers)
#pragma unroll
    for (int p = 0; p < 4; ++p) {
        int e = p*256 + tid;
        gl_lds16(wbuf + (grow + (e >> 3))*512 + h*64 + (e & 7)*8,
                 &WL[(size_t)e*8]);
    }

    // ---- phase 1: fx GEMM, M=128 N=64 K=256 ----
    f32x4 facc[2][4];
#pragma unroll
    for (int i = 0; i < 2; i++)
#pragma unroll
        for (int j = 0; j < 4; j++) facc[i][j] = (f32x4)(0.f);

    int r0 = tid >> 2;
    int kswz = (((tid & 3) ^ ((tid >> 3) & 3))) * 8;

    for (int k0 = 0; k0 < 256; k0 += 32) {
        __syncthreads();
        gl_lds16(Xb + (grow + r0)*256 + k0 + kswz,            &As[(size_t)tid*8]);
        gl_lds16(Xb + (grow + 64 + r0)*256 + k0 + kswz,       &As[(size_t)(tid+256)*8]);
        gl_lds16(Wcatb + (size_t)(h*64 + r0)*256 + k0 + kswz, &Bs[(size_t)tid*8]);
        __syncthreads();
        short8 af[2], bf[4];
#pragma unroll
        for (int i = 0; i < 2; i++)
            af[i] = *(const short8*)&As[(w*32 + i*16 + lr)*32 + lqs*8];
#pragma unroll
        for (int j = 0; j < 4; j++)
            bf[j] = *(const short8*)&Bs[(j*16 + lr)*32 + lqs*8];
#pragma unroll
        for (int i = 0; i < 2; i++)
#pragma unroll
            for (int j = 0; j < 4; j++)
                facc[i][j] = __builtin_amdgcn_mfma_f32_16x16x32_bf16(af[i], bf[j], facc[i][j], 0, 0, 0);
    }

    // ---- phase 2: bias + f2bf -> FX[d][tok] (slot XOR swizzle) ----
    float fbv[4];
#pragma unroll
    for (int j = 0; j < 4; j++) fbv[j] = bcat[h*64 + j*16 + lr];
#pragma unroll
    for (int i = 0; i < 2; i++)
#pragma unroll
        for (int j = 0; j < 4; j++) {
            int d = j*16 + lr;
#pragma unroll
            for (int r = 0; r < 4; r++) {
                int tok = w*32 + i*16 + lq*4 + r;
                int ss = (tok >> 3) ^ ((d >> 1) & 3);
                FX[d*128 + ss*8 + (tok & 7)] = f2bf(facc[i][j][r] + fbv[j]);
            }
        }
    __syncthreads();

    // ---- phase 3: reduce over 128 toks in 4 k-groups of 32 ----
    f32x4 racc[4];
#pragma unroll
    for (int j = 0; j < 4; j++) racc[j] = (f32x4)(0.f);
    float nacc = 0.f;

#pragma unroll
    for (int kk = 0; kk < 4; ++kk) {
        short8 af;
        float ns = 0.f;
#pragma unroll
        for (int e = 0; e < 8; ++e) {
            unsigned short u = WL[(kk*32 + lq*8 + e)*64 + w*16 + lr];
            af[e] = (short)u;
            ns += bf2f(u);
        }
        nacc += ns;
        short8 bfv[4];
#pragma unroll
        for (int j = 0; j < 4; j++) {
            int ss = (kk*4 + lq) ^ ((lr >> 1) & 3);
            bfv[j] = *(const short8*)&FX[(j*16 + lr)*128 + ss*8];
        }
#pragma unroll
        for (int j = 0; j < 4; j++)
            racc[j] = __builtin_amdgcn_mfma_f32_16x16x32_bf16(af, bfv[j], racc[j], 0, 0, 0);
    }

#pragma unroll
    for (int j = 0; j < 4; j++) {
        int d = j*16 + lr;
#pragma unroll
        for (int r = 0; r < 4; r++) {
            int s = w*16 + lq*4 + r;
            atomicAdd(&tok_acc[((size_t)bh*64 + s)*64 + d], racc[j][r]);
        }
    }
    nacc += __shfl_xor(nacc, 16);
    nacc += __shfl_xor(nacc, 32);
    if (lq == 0)
        atomicAdd(&norm_acc[bh*64 + w*16 + lr], nacc);
}

// K3b: per b: kv = mean_h (tok/(norm+1e-5)); kn = rownorm(kv@Wk^T); v = kv@Wv^T
__global__ __launch_bounds__(256) void k_kv(
    const float* __restrict__ tok, const float* __restrict__ norm,
    const float* __restrict__ Wk, const float* __restrict__ Wv,
    float* __restrict__ kn_out, float* __restrict__ v_out)
{
    __shared__ float KV[64][65];
    __shared__ float TMP[64][65];
    __shared__ float rn[64];
    __shared__ float inv[8][64];
    int b = blockIdx.x, tid = threadIdx.x;
    for (int idx = tid; idx < 512; idx += 256) {
        int h = idx >> 6, s = idx & 63;
        inv[h][s] = 1.f / (norm[(b*8 + h)*64 + s] + 1e-5f);
    }
    __syncthreads();
    for (int idx = tid; idx < 4096; idx += 256) {
        int s = idx >> 6;
        float acc = 0.f;
        for (int h = 0; h < 8; ++h)
            acc += tok[((size_t)(b*8 + h))*4096 + idx] * inv[h][s];
        KV[s][idx & 63] = acc * 0.125f;
    }
    __syncthreads();
    for (int idx = tid; idx < 4096; idx += 256) {
        int s = idx >> 6, d = idx & 63;
        float a = 0.f;
        for (int e = 0; e < 64; ++e) a += KV[s][e] * Wk[d*64 + e];
        TMP[s][d] = a;
    }
    __syncthreads();
    if (tid < 64) {
        float a = 0.f;
        for (int d = 0; d < 64; ++d) { float x = TMP[tid][d]; a += x*x; }
        rn[tid] = fmaxf(sqrtf(a), 1e-12f);
    }
    __syncthreads();
    for (int idx = tid; idx < 4096; idx += 256) {
        int s = idx >> 6, d = idx & 63;
        kn_out[(size_t)b*4096 + idx] = TMP[s][d] / rn[s];
    }
    for (int idx = tid; idx < 4096; idx += 256) {
        int s = idx >> 6, d = idx & 63;
        float a = 0.f;
        for (int e = 0; e < 64; ++e) a += KV[s][e] * Wv[d*64 + e];
        v_out[(size_t)b*4096 + idx] = a;
    }
}

// K3c: per (b,h): tn = tok/(norm+1e-5); q = tn@Wq^T, cosine attn vs kn,
// softmax, @v, + srs*tn   (R5 version — mt fusion reverted, it serialized)
__global__ __launch_bounds__(256) void k_attn(
    const float* __restrict__ tok, const float* __restrict__ norm,
    const float* __restrict__ Wq,
    const float* __restrict__ kn, const float* __restrict__ vbuf,
    const float* __restrict__ attn_scale, const float* __restrict__ srs,
    float* __restrict__ out_tok)
{
    __shared__ float TN[64][65];
    __shared__ float Q[64][65];
    __shared__ float KN[64][65];
    __shared__ float L[64][65];
    __shared__ float rn[64];
    int h = blockIdx.x & 7, b = blockIdx.x >> 3;
    int bh = b*8 + h;
    int tid = threadIdx.x;
    for (int idx = tid; idx < 4096; idx += 256) {
        int g = idx >> 6;
        TN[g][idx & 63] = tok[(size_t)bh*4096 + idx] / (norm[bh*64 + g] + 1e-5f);
        KN[g][idx & 63] = kn[(size_t)b*4096 + idx];
    }
    __syncthreads();
    for (int idx = tid; idx < 4096; idx += 256) {
        int g = idx >> 6, d = idx & 63;
        float a = 0.f;
        for (int e = 0; e < 64; ++e) a += TN[g][e] * Wq[d*64 + e];
        Q[g][d] = a;
    }
    __syncthreads();
    if (tid < 64) {
        float a = 0.f;
        for (int d = 0; d < 64; ++d) { float x = Q[tid][d]; a += x*x; }
        rn[tid] = fmaxf(sqrtf(a), 1e-12f);
    }
    __syncthreads();
    float scale = attn_scale[h];
    for (int idx = tid; idx < 4096; idx += 256) {
        int g = idx >> 6, s = idx & 63;
        float a = 0.f;
        for (int e = 0; e < 64; ++e) a += Q[g][e] * KN[s][e];
        L[g][s] = a / rn[g] * scale;
    }
    __syncthreads();
    if (tid < 64) {
        float mx = -1e30f;
        for (int s = 0; s < 64; ++s) mx = fmaxf(mx, L[tid][s]);
        float sm = 0.f;
        for (int s = 0; s < 64; ++s) { float e = expf(L[tid][s]-mx); L[tid][s] = e; sm += e; }
        float ivv = 1.f/sm;
        for (int s = 0; s < 64; ++s) L[tid][s] *= ivv;
    }
    __syncthreads();
    float srsv = srs[0];
    for (int idx = tid; idx < 4096; idx += 256) {
        int g = idx >> 6, d = idx & 63;
        float a = 0.f;
        for (int s = 0; s < 64; ++s) a += L[g][s] * vbuf[(size_t)b*4096 + s*64 + d];
        out_tok[(size_t)bh*4096 + idx] = a + srsv * TN[g][d];
    }
}

// K3d: MTb[b][j][h*64+s] = sum_d out_tok[b,h,s,d] * Wout[j, h*64+d]  (bf16 out)
__global__ __launch_bounds__(256) void k_mt(
    const float* __restrict__ out_tok, const float* __restrict__ Wout,
    unsigned short* __restrict__ MTb)
{
    __shared__ float Wt[64][68];   // [d][j]
    __shared__ float Ot[64][68];   // [d][s]
    int jt = blockIdx.x, h = blockIdx.y, b = blockIdx.z;
    int j0 = jt * 64;
    int tid = threadIdx.x;
    int tx = tid & 15, ty = tid >> 4;
#pragma unroll
    for (int i = 0; i < 4; i++) {
        int flat = tid + i*256;
        int r = flat >> 4;
        int c4 = (flat & 15) * 4;
        float4 wv = *(const float4*)(Wout + (size_t)(j0+r)*512 + h*64 + c4);
        Wt[c4+0][r]=wv.x; Wt[c4+1][r]=wv.y; Wt[c4+2][r]=wv.z; Wt[c4+3][r]=wv.w;
        float4 ov = *(const float4*)(out_tok + ((size_t)(b*8+h)*64 + r)*64 + c4);
        Ot[c4+0][r]=ov.x; Ot[c4+1][r]=ov.y; Ot[c4+2][r]=ov.z; Ot[c4+3][r]=ov.w;
    }
    __syncthreads();
    float acc[4][4] = {{0.f}};
#pragma unroll 8
    for (int d = 0; d < 64; ++d) {
        float av[4], bv[4];
        *(float4*)av = *(const float4*)&Wt[d][ty*4];
        *(float4*)bv = *(const float4*)&Ot[d][tx*4];
#pragma unroll
        for (int i = 0; i < 4; i++)
#pragma unroll
            for (int j = 0; j < 4; j++) acc[i][j] += av[i]*bv[j];
    }
#pragma unroll
    for (int i = 0; i < 4; i++) {
        int j = j0 + ty*4 + i;
#pragma unroll
        for (int jj = 0; jj < 4; jj++) {
            int s = tx*4 + jj;
            MTb[((size_t)(b*256) + j)*512 + h*64 + s] = f2bf(acc[i][jj]);
        }
    }
}

// ---------------------------------------------------------------------------
// K5: MFMA GEMM. out[65536 x 256] = wbuf(bf16) @ MTb[b]^T + bout (fp32 out)
// Slot swizzle + counted-vmcnt pipeline (verified).
// ---------------------------------------------------------------------------
__global__ __launch_bounds__(256) void k_gemm2(
    const unsigned short* __restrict__ A, const unsigned short* __restrict__ Ball,
    const float* __restrict__ bias, float* __restrict__ C)
{
    __shared__ unsigned short As[2][128*32];
    __shared__ unsigned short Bs[2][128*32];
    int bid = blockIdx.x;             // 1024
    int xcd = bid & 7;
    int inner = bid >> 3;             // 0..127
    int rt = xcd*64 + (inner >> 1);   // 0..511
    int ct = inner & 1;
    int m0 = rt*128, n0 = ct*128;
    const unsigned short* Bm = Ball + (size_t)(m0 >> 14) * 256 * 512;
    int tid = threadIdx.x;
    int lane = tid & 63, w = tid >> 6;
    int wr = w >> 1, wc = w & 1;
    int lr = lane & 15, lq = lane >> 4;
    int lqs = lq ^ ((lr >> 1) & 3);

    f32x4 acc[4][4];
#pragma unroll
    for (int i = 0; i < 4; i++)
#pragma unroll
        for (int j = 0; j < 4; j++) acc[i][j] = (f32x4)(0.f);

    int r0 = tid >> 2;
    int kswz = (((tid & 3) ^ ((tid >> 3) & 3))) * 8;

    auto stage = [&](int buf, int k0) {
        gl_lds16(A + (size_t)(m0 + r0)*512 + k0 + kswz,       &As[buf][(size_t)tid*8]);
        gl_lds16(A + (size_t)(m0 + 64 + r0)*512 + k0 + kswz,  &As[buf][(size_t)(tid+256)*8]);
        gl_lds16(Bm + (size_t)(n0 + r0)*512 + k0 + kswz,      &Bs[buf][(size_t)tid*8]);
        gl_lds16(Bm + (size_t)(n0 + 64 + r0)*512 + k0 + kswz, &Bs[buf][(size_t)(tid+256)*8]);
    };

    stage(0, 0);
    stage(1, 32);
    int cur = 0;
#pragma unroll
    for (int t = 0; t < 16; ++t) {
        if (t < 15) { WAIT_VM(4); } else { WAIT_VM(0); }
        __builtin_amdgcn_s_barrier();
        short8 af[4], bf[4];
#pragma unroll
        for (int i = 0; i < 4; i++) {
            af[i] = *(const short8*)&As[cur][(wr*64 + i*16 + lr)*32 + lqs*8];
            bf[i] = *(const short8*)&Bs[cur][(wc*64 + i*16 + lr)*32 + lqs*8];
        }
        WAIT_LGKM0();
        __builtin_amdgcn_sched_barrier(0);
        __builtin_amdgcn_s_barrier();
        if (t < 14) stage(cur, (t + 2) * 32);
#pragma unroll
        for (int i = 0; i < 4; i++)
#pragma unroll
            for (int j = 0; j < 4; j++)
                acc[i][j] = __builtin_amdgcn_mfma_f32_16x16x32_bf16(af[i], bf[j], acc[i][j], 0, 0, 0);
        cur ^= 1;
    }

#pragma unroll
    for (int j = 0; j < 4; j++) {
        int n = n0 + wc*64 + j*16 + lr;
        float bv = bias[n];
#pragma unroll
        for (int i = 0; i < 4; i++) {
            int mrow = m0 + wr*64 + i*16 + lq*4;
#pragma unroll
            for (int r = 0; r < 4; r++)
                C[(size_t)(mrow + r)*256 + n] = acc[i][j][r] + bv;
        }
    }
}

// ---------------------------------------------------------------------------
extern "C" void kernel_launch(void* const* d_in, const int* in_sizes, int n_in,
                              void* d_out, int out_size, void* d_ws, size_t ws_size,
                              hipStream_t stream)
{
    const float* x      = (const float*)d_in[0];
    const float* Wx     = (const float*)d_in[1];
    const float* bx     = (const float*)d_in[2];
    const float* Wfx    = (const float*)d_in[3];
    const float* bfx    = (const float*)d_in[4];
    const float* Wslice = (const float*)d_in[5];
    const float* bslice = (const float*)d_in[6];
    const float* temperature = (const float*)d_in[7];
    const float* Wq     = (const float*)d_in[8];
    const float* Wk     = (const float*)d_in[9];
    const float* Wv     = (const float*)d_in[10];
    const float* attn_scale = (const float*)d_in[11];
    const float* srs    = (const float*)d_in[12];
    const float* Wout   = (const float*)d_in[13];
    const float* bout   = (const float*)d_in[14];
    float* out = (float*)d_out;
    float* ws  = (float*)d_ws;

    // workspace layout (float offsets)
    float* tok  = ws + 0;          // 131072
    float* norm = ws + 131072;     // 2048
    float* bcat = ws + 133120;     // 1024
    float* kn   = ws + 134144;     // 16384
    float* vb   = ws + 150528;     // 16384
    float* ot   = ws + 166912;     // 131072
    unsigned short* Wcatb = (unsigned short*)(ws + 297984);  // 1024*256  -> 131072 floats
    unsigned short* MTb   = (unsigned short*)(ws + 429056);  // 4*256*512 -> 262144 floats
    unsigned short* xb    = (unsigned short*)(ws + 691200);  // 65536*256 -> 8388608 floats
    unsigned short* wbuf  = (unsigned short*)(ws + 9079808); // 65536*512 -> 16777216 floats

    hipMemsetAsync(tok, 0, 133120 * sizeof(float), stream);  // tok_acc + norm
    k_prep<<<1024, 64, 0, stream>>>(Wx, bx, Wfx, bfx, Wslice, bslice, Wcatb, bcat);
    k_xcast<<<8192, 256, 0, stream>>>(x, xb);
    k_gemm1<<<2048, 256, 0, stream>>>(xb, Wcatb, bcat, temperature, wbuf);
    k_tok<<<dim3(128, 32), 256, 0, stream>>>(xb, Wcatb, bcat, wbuf, tok, norm);
    k_kv<<<4, 256, 0, stream>>>(tok, norm, Wk, Wv, kn, vb);
    k_attn<<<32, 256, 0, stream>>>(tok, norm, Wq, kn, vb, attn_scale, srs, ot);
    k_mt<<<dim3(4, 8, 4), 256, 0, stream>>>(ot, Wout, MTb);
    k_gemm2<<<1024, 256, 0, stream>>>(wbuf, MTb, bout, out);
}

// Round 8
// 365.455 us; speedup vs baseline: 1.0879x; 1.0879x over previous
//
#include <hip/hip_runtime.h>
#include <math.h>

// Problem constants (Physics_Attention_Irregular_Mesh)
#define BQ   4
#define NTOK 16384
#define DIMM 256
#define HH   8
#define DDIM 64
#define SSL  64
#define INNERD 512
#define BN_TOK (BQ*NTOK)   // 65536

typedef __attribute__((ext_vector_type(8))) short short8;   // 8 bf16 (4 VGPRs)
typedef __attribute__((ext_vector_type(4))) float f32x4;    // 4 fp32 acc

// bf16 <-> f32 helpers (RNE)
__device__ inline float bf2f(unsigned short u) {
    union { float f; unsigned int i; } v; v.i = ((unsigned int)u) << 16; return v.f;
}
__device__ inline unsigned short f2bf(float f) {
    union { float f; unsigned int i; } v; v.f = f;
    unsigned int r = v.i + 0x7FFFu + ((v.i >> 16) & 1u);
    return (unsigned short)(r >> 16);
}

// async global->LDS, 16 B per lane (wave-uniform LDS base + lane*16)
__device__ __forceinline__ void gl_lds16(const void* g, void* l) {
    __builtin_amdgcn_global_load_lds(
        (const __attribute__((address_space(1))) unsigned int*)g,
        (__attribute__((address_space(3))) unsigned int*)l, 16, 0, 0);
}

#define WAIT_VM(N) asm volatile("s_waitcnt vmcnt(" #N ")" ::: "memory")
#define WAIT_LGKM0() asm volatile("s_waitcnt lgkmcnt(0)" ::: "memory")

// ---------------------------------------------------------------------------
// K0: merged weights (bf16 out).
// ---------------------------------------------------------------------------
__global__ void k_prep(const float* __restrict__ Wx, const float* __restrict__ bx,
                       const float* __restrict__ Wfx, const float* __restrict__ bfx,
                       const float* __restrict__ Wslice, const float* __restrict__ bslice,
                       unsigned short* __restrict__ Wcatb, float* __restrict__ bcat)
{
    int row = blockIdx.x;   // 0..1023
    int t = threadIdx.x;    // 64
    if (row < 512) {
        for (int c = t; c < 256; c += 64) Wcatb[row*256 + c] = f2bf(Wfx[row*256 + c]);
        if (t == 0) bcat[row] = bfx[row];
    } else {
        int r = row - 512, h = r >> 6, s = r & 63;
        for (int c = t; c < 256; c += 64) {
            float acc = 0.f;
            for (int d = 0; d < 64; ++d)
                acc += Wslice[s*64 + d] * Wx[(h*64 + d)*256 + c];
            Wcatb[row*256 + c] = f2bf(acc);
        }
        if (t == 0) {
            float acc = bslice[s];
            for (int d = 0; d < 64; ++d) acc += Wslice[s*64 + d] * bx[h*64 + d];
            bcat[row] = acc;
        }
    }
}

// x (fp32) -> xb (bf16), 8 elems/thread
__global__ void k_xcast(const float* __restrict__ x, unsigned short* __restrict__ xb)
{
    size_t i = ((size_t)blockIdx.x*256 + threadIdx.x)*8;
    float4 a = *(const float4*)(x + i);
    float4 b = *(const float4*)(x + i + 4);
    *(ushort4*)(xb + i)     = make_ushort4(f2bf(a.x), f2bf(a.y), f2bf(a.z), f2bf(a.w));
    *(ushort4*)(xb + i + 4) = make_ushort4(f2bf(b.x), f2bf(b.y), f2bf(b.z), f2bf(b.w));
}

// ---------------------------------------------------------------------------
// K1: MFMA GEMM C[65536 x 1024] = xb @ Wcatb^T + bcat, fused epilogues:
//   cols 0..511   -> fx_t[b,h,d,n] (bf16, transposed for k_tok)
//   cols 512..1023-> per-head softmax -> wbuf[token][h*64+s]
// OCCUPANCY RESTRUCTURE: 512 threads / 8 waves, wave tile 32x64 ->
// acc[2][4] = 32 AGPR; with launch_bounds(512,4) total regs <=128, crossing
// the m69 register cliff (was 84 VGPR + 64 AGPR = 148 -> 2 waves/SIMD).
// Per-element math/K-order/fragments identical to the verified 4-wave code.
// ---------------------------------------------------------------------------
__global__ __launch_bounds__(512, 4) void k_gemm1(
    const unsigned short* __restrict__ Xb, const unsigned short* __restrict__ Wb,
    const float* __restrict__ bias, const float* __restrict__ temperature,
    unsigned short* __restrict__ fx_t, unsigned short* __restrict__ wbuf)
{
    __shared__ unsigned short As[2][128*32];
    __shared__ unsigned short Bs[2][128*32];
    int bid = blockIdx.x;             // 4096
    int xcd = bid & 7;
    int inner = bid >> 3;             // temporal order within one XCD
    int rt = xcd*64 + (inner >> 3);   // 0..511
    int ct = inner & 7;               // 0..7
    int m0 = rt*128, n0 = ct*128;
    int tid = threadIdx.x;            // 0..511
    int lane = tid & 63, w = tid >> 6;    // 8 waves
    int wrow = w >> 1, wcol = w & 1;      // 4x2 wave grid, wave tile 32x64
    int lr = lane & 15, lq = lane >> 4;
    int lqs = lq ^ ((lr >> 1) & 3);   // swizzled read slot (verified, 0 conflicts)

    f32x4 acc[2][4];
#pragma unroll
    for (int i = 0; i < 2; i++)
#pragma unroll
        for (int j = 0; j < 4; j++) acc[i][j] = (f32x4)(0.f);

    int r0 = tid >> 2;                                  // 0..127
    int kswz = (((tid & 3) ^ ((tid >> 3) & 3))) * 8;    // pre-swizzled source slot

    auto stage = [&](int buf, int k0) {
        gl_lds16(Xb + (size_t)(m0 + r0)*256 + k0 + kswz, &As[buf][(size_t)tid*8]);
        gl_lds16(Wb + (size_t)(n0 + r0)*256 + k0 + kswz, &Bs[buf][(size_t)tid*8]);
    };

    stage(0, 0);
    stage(1, 32);      // 4 vmem ops in flight per wave
    int cur = 0;
#pragma unroll
    for (int t = 0; t < 8; ++t) {
        if (t < 7) { WAIT_VM(2); } else { WAIT_VM(0); }
        __builtin_amdgcn_s_barrier();        // buf[cur] ready for all waves
        short8 af[2], bf[4];
#pragma unroll
        for (int i = 0; i < 2; i++)
            af[i] = *(const short8*)&As[cur][(wrow*32 + i*16 + lr)*32 + lqs*8];
#pragma unroll
        for (int j = 0; j < 4; j++)
            bf[j] = *(const short8*)&Bs[cur][(wcol*64 + j*16 + lr)*32 + lqs*8];
        WAIT_LGKM0();
        __builtin_amdgcn_sched_barrier(0);
        __builtin_amdgcn_s_barrier();        // all waves done reading buf[cur]
        if (t < 6) stage(cur, (t + 2) * 32); // overwrite cur for iter t+2
#pragma unroll
        for (int i = 0; i < 2; i++)
#pragma unroll
            for (int j = 0; j < 4; j++)
                acc[i][j] = __builtin_amdgcn_mfma_f32_16x16x32_bf16(af[i], bf[j], acc[i][j], 0, 0, 0);
        cur ^= 1;
    }

    float bv[4];
#pragma unroll
    for (int j = 0; j < 4; j++) bv[j] = bias[n0 + wcol*64 + j*16 + lr];

    if (n0 < 512) {
        // fx half: write transposed fx_t[(batch*8+h)*64+d][token]
        int h = (n0 + wcol*64) >> 6;
        int batch = m0 >> 14;
#pragma unroll
        for (int i = 0; i < 2; i++) {
            int tokbase = m0 + wrow*32 + i*16 + lq*4;
            int nloc = tokbase & (NTOK-1);
#pragma unroll
            for (int j = 0; j < 4; j++) {
                int d = j*16 + lr;
                ushort4 pk = make_ushort4(
                    f2bf(acc[i][j][0] + bv[j]), f2bf(acc[i][j][1] + bv[j]),
                    f2bf(acc[i][j][2] + bv[j]), f2bf(acc[i][j][3] + bv[j]));
                *(ushort4*)(fx_t + ((size_t)(batch*8 + h)*64 + d)*NTOK + nloc) = pk;
            }
        }
    } else {
        // logits half: per-row softmax over this head's 64 cols
        int h = (n0 - 512 + wcol*64) >> 6;
        float it = 1.f / fmaxf(temperature[h], 1e-4f);
        int colbase = (n0 - 512) + wcol*64;
#pragma unroll
        for (int i = 0; i < 2; i++) {
            int tokbase = m0 + wrow*32 + i*16 + lq*4;
#pragma unroll
            for (int r = 0; r < 4; r++) {
                float v[4];
#pragma unroll
                for (int j = 0; j < 4; j++) v[j] = (acc[i][j][r] + bv[j]) * it;
                float mx = fmaxf(fmaxf(v[0], v[1]), fmaxf(v[2], v[3]));
                mx = fmaxf(mx, __shfl_xor(mx, 1));
                mx = fmaxf(mx, __shfl_xor(mx, 2));
                mx = fmaxf(mx, __shfl_xor(mx, 4));
                mx = fmaxf(mx, __shfl_xor(mx, 8));
                float e[4], sm = 0.f;
#pragma unroll
                for (int j = 0; j < 4; j++) { e[j] = __expf(v[j] - mx); sm += e[j]; }
                sm += __shfl_xor(sm, 1);
                sm += __shfl_xor(sm, 2);
                sm += __shfl_xor(sm, 4);
                sm += __shfl_xor(sm, 8);
                float inv = 1.f / sm;
                size_t rowoff = (size_t)(tokbase + r)*512 + colbase + lr;
#pragma unroll
                for (int j = 0; j < 4; j++)
                    wbuf[rowoff + j*16] = f2bf(e[j] * inv);
            }
        }
    }
}

// ---------------------------------------------------------------------------
// K2: MFMA tok-reduction (R6 verified version). Per (b,h):
// C[64s x 64d] = sum_n w[n][s] fx[n][d]; norm from af registers.
// ---------------------------------------------------------------------------
__global__ __launch_bounds__(256) void k_tok(
    const unsigned short* __restrict__ wbuf, const unsigned short* __restrict__ fx_t,
    float* __restrict__ tok_acc, float* __restrict__ norm_acc)
{
    __shared__ unsigned short As[2][32*64];   // [token][s]  (linear gl_lds16 dest)
    __shared__ unsigned short Bs[2][64*32];   // [d][token slots swizzled]
    int chunk = blockIdx.x;   // 0..31
    int bh = blockIdx.y;      // 0..31
    int b = bh >> 3, h = bh & 7;
    int n0 = chunk * 512;
    int tid = threadIdx.x;
    int lane = tid & 63, w = tid >> 6;
    int lr = lane & 15, lq = lane >> 4;
    int lqs = lq ^ ((lr >> 1) & 3);

    f32x4 acc[4];
#pragma unroll
    for (int j = 0; j < 4; j++) acc[j] = (f32x4)(0.f);
    float nacc = 0.f;

    const unsigned short* wsrc =
        wbuf + ((size_t)(b*NTOK + n0 + (tid >> 3)))*512 + h*64 + (tid & 7)*8;
    int kswz = (((tid & 3) ^ ((tid >> 3) & 3))) * 8;
    const unsigned short* fsrc =
        fx_t + ((size_t)bh*64 + (tid >> 2))*NTOK + n0 + kswz;

    auto stage = [&](int buf, int kk) {
        gl_lds16(wsrc + (size_t)kk*512, &As[buf][(size_t)tid*8]);
        gl_lds16(fsrc + kk,             &Bs[buf][(size_t)tid*8]);
    };

    stage(0, 0);
    stage(1, 32);     // 4 vmem ops in flight per wave
    int cur = 0;
#pragma unroll
    for (int t = 0; t < 16; ++t) {
        if (t < 15) { WAIT_VM(2); } else { WAIT_VM(0); }
        __builtin_amdgcn_s_barrier();
        // af[e] = w[tok = lq*8+e][s = w*16+lr]
        const unsigned short* arow = &As[cur][w*16 + lr];
        short8 af;
#pragma unroll
        for (int e = 0; e < 8; ++e)
            af[e] = (short)arow[(lq*8 + e)*64];
        short8 bfv[4];
#pragma unroll
        for (int j = 0; j < 4; j++)
            bfv[j] = *(const short8*)&Bs[cur][(j*16 + lr)*32 + lqs*8];
        WAIT_LGKM0();
        __builtin_amdgcn_sched_barrier(0);
        __builtin_amdgcn_s_barrier();
        if (t < 14) stage(cur, (t + 2) * 32);

        float ns = 0.f;
#pragma unroll
        for (int e = 0; e < 8; ++e) ns += bf2f((unsigned short)af[e]);
        nacc += ns;
#pragma unroll
        for (int j = 0; j < 4; j++)
            acc[j] = __builtin_amdgcn_mfma_f32_16x16x32_bf16(af, bfv[j], acc[j], 0, 0, 0);
        cur ^= 1;
    }

#pragma unroll
    for (int j = 0; j < 4; j++) {
        int d = j*16 + lr;
#pragma unroll
        for (int r = 0; r < 4; r++) {
            int s = w*16 + lq*4 + r;
            atomicAdd(&tok_acc[((size_t)bh*64 + s)*64 + d], acc[j][r]);
        }
    }
    nacc += __shfl_xor(nacc, 16);
    nacc += __shfl_xor(nacc, 32);
    if (lq == 0)
        atomicAdd(&norm_acc[bh*64 + w*16 + lr], nacc);
}

// K3b: per b: kv = mean_h (tok/(norm+1e-5)); kn = rownorm(kv@Wk^T); v = kv@Wv^T
__global__ __launch_bounds__(256) void k_kv(
    const float* __restrict__ tok, const float* __restrict__ norm,
    const float* __restrict__ Wk, const float* __restrict__ Wv,
    float* __restrict__ kn_out, float* __restrict__ v_out)
{
    __shared__ float KV[64][65];
    __shared__ float TMP[64][65];
    __shared__ float rn[64];
    __shared__ float inv[8][64];
    int b = blockIdx.x, tid = threadIdx.x;
    for (int idx = tid; idx < 512; idx += 256) {
        int h = idx >> 6, s = idx & 63;
        inv[h][s] = 1.f / (norm[(b*8 + h)*64 + s] + 1e-5f);
    }
    __syncthreads();
    for (int idx = tid; idx < 4096; idx += 256) {
        int s = idx >> 6;
        float acc = 0.f;
        for (int h = 0; h < 8; ++h)
            acc += tok[((size_t)(b*8 + h))*4096 + idx] * inv[h][s];
        KV[s][idx & 63] = acc * 0.125f;
    }
    __syncthreads();
    for (int idx = tid; idx < 4096; idx += 256) {
        int s = idx >> 6, d = idx & 63;
        float a = 0.f;
        for (int e = 0; e < 64; ++e) a += KV[s][e] * Wk[d*64 + e];
        TMP[s][d] = a;
    }
    __syncthreads();
    if (tid < 64) {
        float a = 0.f;
        for (int d = 0; d < 64; ++d) { float x = TMP[tid][d]; a += x*x; }
        rn[tid] = fmaxf(sqrtf(a), 1e-12f);
    }
    __syncthreads();
    for (int idx = tid; idx < 4096; idx += 256) {
        int s = idx >> 6, d = idx & 63;
        kn_out[(size_t)b*4096 + idx] = TMP[s][d] / rn[s];
    }
    for (int idx = tid; idx < 4096; idx += 256) {
        int s = idx >> 6, d = idx & 63;
        float a = 0.f;
        for (int e = 0; e < 64; ++e) a += KV[s][e] * Wv[d*64 + e];
        v_out[(size_t)b*4096 + idx] = a;
    }
}

// K3c: per (b,h): tn = tok/(norm+1e-5); q = tn@Wq^T, cosine attn vs kn,
// softmax, @v, + srs*tn
__global__ __launch_bounds__(256) void k_attn(
    const float* __restrict__ tok, const float* __restrict__ norm,
    const float* __restrict__ Wq,
    const float* __restrict__ kn, const float* __restrict__ vbuf,
    const float* __restrict__ attn_scale, const float* __restrict__ srs,
    float* __restrict__ out_tok)
{
    __shared__ float TN[64][65];
    __shared__ float Q[64][65];
    __shared__ float KN[64][65];
    __shared__ float L[64][65];
    __shared__ float rn[64];
    int h = blockIdx.x & 7, b = blockIdx.x >> 3;
    int bh = b*8 + h;
    int tid = threadIdx.x;
    for (int idx = tid; idx < 4096; idx += 256) {
        int g = idx >> 6;
        TN[g][idx & 63] = tok[(size_t)bh*4096 + idx] / (norm[bh*64 + g] + 1e-5f);
        KN[g][idx & 63] = kn[(size_t)b*4096 + idx];
    }
    __syncthreads();
    for (int idx = tid; idx < 4096; idx += 256) {
        int g = idx >> 6, d = idx & 63;
        float a = 0.f;
        for (int e = 0; e < 64; ++e) a += TN[g][e] * Wq[d*64 + e];
        Q[g][d] = a;
    }
    __syncthreads();
    if (tid < 64) {
        float a = 0.f;
        for (int d = 0; d < 64; ++d) { float x = Q[tid][d]; a += x*x; }
        rn[tid] = fmaxf(sqrtf(a), 1e-12f);
    }
    __syncthreads();
    float scale = attn_scale[h];
    for (int idx = tid; idx < 4096; idx += 256) {
        int g = idx >> 6, s = idx & 63;
        float a = 0.f;
        for (int e = 0; e < 64; ++e) a += Q[g][e] * KN[s][e];
        L[g][s] = a / rn[g] * scale;
    }
    __syncthreads();
    if (tid < 64) {
        float mx = -1e30f;
        for (int s = 0; s < 64; ++s) mx = fmaxf(mx, L[tid][s]);
        float sm = 0.f;
        for (int s = 0; s < 64; ++s) { float e = expf(L[tid][s]-mx); L[tid][s] = e; sm += e; }
        float ivv = 1.f/sm;
        for (int s = 0; s < 64; ++s) L[tid][s] *= ivv;
    }
    __syncthreads();
    float srsv = srs[0];
    for (int idx = tid; idx < 4096; idx += 256) {
        int g = idx >> 6, d = idx & 63;
        float a = 0.f;
        for (int s = 0; s < 64; ++s) a += L[g][s] * vbuf[(size_t)b*4096 + s*64 + d];
        out_tok[(size_t)bh*4096 + idx] = a + srsv * TN[g][d];
    }
}

// K3d: MTb[b][j][h*64+s] = sum_d out_tok[b,h,s,d] * Wout[j, h*64+d]  (bf16 out)
__global__ __launch_bounds__(256) void k_mt(
    const float* __restrict__ out_tok, const float* __restrict__ Wout,
    unsigned short* __restrict__ MTb)
{
    __shared__ float Wt[64][68];   // [d][j]
    __shared__ float Ot[64][68];   // [d][s]
    int jt = blockIdx.x, h = blockIdx.y, b = blockIdx.z;
    int j0 = jt * 64;
    int tid = threadIdx.x;
    int tx = tid & 15, ty = tid >> 4;
#pragma unroll
    for (int i = 0; i < 4; i++) {
        int flat = tid + i*256;
        int r = flat >> 4;
        int c4 = (flat & 15) * 4;
        float4 wv = *(const float4*)(Wout + (size_t)(j0+r)*512 + h*64 + c4);
        Wt[c4+0][r]=wv.x; Wt[c4+1][r]=wv.y; Wt[c4+2][r]=wv.z; Wt[c4+3][r]=wv.w;
        float4 ov = *(const float4*)(out_tok + ((size_t)(b*8+h)*64 + r)*64 + c4);
        Ot[c4+0][r]=ov.x; Ot[c4+1][r]=ov.y; Ot[c4+2][r]=ov.z; Ot[c4+3][r]=ov.w;
    }
    __syncthreads();
    float acc[4][4] = {{0.f}};
#pragma unroll 8
    for (int d = 0; d < 64; ++d) {
        float av[4], bv[4];
        *(float4*)av = *(const float4*)&Wt[d][ty*4];
        *(float4*)bv = *(const float4*)&Ot[d][tx*4];
#pragma unroll
        for (int i = 0; i < 4; i++)
#pragma unroll
            for (int j = 0; j < 4; j++) acc[i][j] += av[i]*bv[j];
    }
#pragma unroll
    for (int i = 0; i < 4; i++) {
        int j = j0 + ty*4 + i;
#pragma unroll
        for (int jj = 0; jj < 4; jj++) {
            int s = tx*4 + jj;
            MTb[((size_t)(b*256) + j)*512 + h*64 + s] = f2bf(acc[i][jj]);
        }
    }
}

// ---------------------------------------------------------------------------
// K5: MFMA GEMM. out[65536 x 256] = wbuf(bf16) @ MTb[b]^T + bout (fp32 out)
// Same 8-wave / acc[2][4] occupancy restructure as k_gemm1.
// ---------------------------------------------------------------------------
__global__ __launch_bounds__(512, 4) void k_gemm2(
    const unsigned short* __restrict__ A, const unsigned short* __restrict__ Ball,
    const float* __restrict__ bias, float* __restrict__ C)
{
    __shared__ unsigned short As[2][128*32];
    __shared__ unsigned short Bs[2][128*32];
    int bid = blockIdx.x;             // 1024
    int xcd = bid & 7;
    int inner = bid >> 3;             // 0..127
    int rt = xcd*64 + (inner >> 1);   // 0..511
    int ct = inner & 1;
    int m0 = rt*128, n0 = ct*128;
    const unsigned short* Bm = Ball + (size_t)(m0 >> 14) * 256 * 512;
    int tid = threadIdx.x;            // 0..511
    int lane = tid & 63, w = tid >> 6;
    int wrow = w >> 1, wcol = w & 1;
    int lr = lane & 15, lq = lane >> 4;
    int lqs = lq ^ ((lr >> 1) & 3);

    f32x4 acc[2][4];
#pragma unroll
    for (int i = 0; i < 2; i++)
#pragma unroll
        for (int j = 0; j < 4; j++) acc[i][j] = (f32x4)(0.f);

    int r0 = tid >> 2;
    int kswz = (((tid & 3) ^ ((tid >> 3) & 3))) * 8;

    auto stage = [&](int buf, int k0) {
        gl_lds16(A + (size_t)(m0 + r0)*512 + k0 + kswz,  &As[buf][(size_t)tid*8]);
        gl_lds16(Bm + (size_t)(n0 + r0)*512 + k0 + kswz, &Bs[buf][(size_t)tid*8]);
    };

    stage(0, 0);
    stage(1, 32);
    int cur = 0;
#pragma unroll
    for (int t = 0; t < 16; ++t) {
        if (t < 15) { WAIT_VM(2); } else { WAIT_VM(0); }
        __builtin_amdgcn_s_barrier();
        short8 af[2], bf[4];
#pragma unroll
        for (int i = 0; i < 2; i++)
            af[i] = *(const short8*)&As[cur][(wrow*32 + i*16 + lr)*32 + lqs*8];
#pragma unroll
        for (int j = 0; j < 4; j++)
            bf[j] = *(const short8*)&Bs[cur][(wcol*64 + j*16 + lr)*32 + lqs*8];
        WAIT_LGKM0();
        __builtin_amdgcn_sched_barrier(0);
        __builtin_amdgcn_s_barrier();
        if (t < 14) stage(cur, (t + 2) * 32);
#pragma unroll
        for (int i = 0; i < 2; i++)
#pragma unroll
            for (int j = 0; j < 4; j++)
                acc[i][j] = __builtin_amdgcn_mfma_f32_16x16x32_bf16(af[i], bf[j], acc[i][j], 0, 0, 0);
        cur ^= 1;
    }

#pragma unroll
    for (int j = 0; j < 4; j++) {
        int n = n0 + wcol*64 + j*16 + lr;
        float bv = bias[n];
#pragma unroll
        for (int i = 0; i < 2; i++) {
            int mrow = m0 + wrow*32 + i*16 + lq*4;
#pragma unroll
            for (int r = 0; r < 4; r++)
                C[(size_t)(mrow + r)*256 + n] = acc[i][j][r] + bv;
        }
    }
}

// ---------------------------------------------------------------------------
extern "C" void kernel_launch(void* const* d_in, const int* in_sizes, int n_in,
                              void* d_out, int out_size, void* d_ws, size_t ws_size,
                              hipStream_t stream)
{
    const float* x      = (const float*)d_in[0];
    const float* Wx     = (const float*)d_in[1];
    const float* bx     = (const float*)d_in[2];
    const float* Wfx    = (const float*)d_in[3];
    const float* bfx    = (const float*)d_in[4];
    const float* Wslice = (const float*)d_in[5];
    const float* bslice = (const float*)d_in[6];
    const float* temperature = (const float*)d_in[7];
    const float* Wq     = (const float*)d_in[8];
    const float* Wk     = (const float*)d_in[9];
    const float* Wv     = (const float*)d_in[10];
    const float* attn_scale = (const float*)d_in[11];
    const float* srs    = (const float*)d_in[12];
    const float* Wout   = (const float*)d_in[13];
    const float* bout   = (const float*)d_in[14];
    float* out = (float*)d_out;
    float* ws  = (float*)d_ws;

    // workspace layout (float offsets)
    float* tok  = ws + 0;          // 131072
    float* norm = ws + 131072;     // 2048
    float* bcat = ws + 133120;     // 1024
    float* kn   = ws + 134144;     // 16384
    float* vb   = ws + 150528;     // 16384
    float* ot   = ws + 166912;     // 131072
    unsigned short* Wcatb = (unsigned short*)(ws + 297984);  // 1024*256  -> 131072 floats
    unsigned short* MTb   = (unsigned short*)(ws + 429056);  // 4*256*512 -> 262144 floats
    unsigned short* xb    = (unsigned short*)(ws + 691200);  // 65536*256 -> 8388608 floats
    unsigned short* wbuf  = (unsigned short*)(ws + 9079808); // 65536*512 -> 16777216 floats
    unsigned short* fx_t  = (unsigned short*)d_out;          // 64 MiB scratch, consumed by k_tok

    hipMemsetAsync(tok, 0, 133120 * sizeof(float), stream);  // tok_acc + norm
    k_prep<<<1024, 64, 0, stream>>>(Wx, bx, Wfx, bfx, Wslice, bslice, Wcatb, bcat);
    k_xcast<<<8192, 256, 0, stream>>>(x, xb);
    k_gemm1<<<4096, 512, 0, stream>>>(xb, Wcatb, bcat, temperature, fx_t, wbuf);
    k_tok<<<dim3(32, 32), 256, 0, stream>>>(wbuf, fx_t, tok, norm);
    k_kv<<<4, 256, 0, stream>>>(tok, norm, Wk, Wv, kn, vb);
    k_attn<<<32, 256, 0, stream>>>(tok, norm, Wq, kn, vb, attn_scale, srs, ot);
    k_mt<<<dim3(4, 8, 4), 256, 0, stream>>>(ot, Wout, MTb);
    k_gemm2<<<1024, 512, 0, stream>>>(wbuf, MTb, bout, out);
}

// Round 9
// 358.583 us; speedup vs baseline: 1.1088x; 1.0192x over previous
//
#include <hip/hip_runtime.h>
#include <math.h>

// Problem constants (Physics_Attention_Irregular_Mesh)
#define BQ   4
#define NTOK 16384
#define DIMM 256
#define HH   8
#define DDIM 64
#define SSL  64
#define INNERD 512
#define BN_TOK (BQ*NTOK)   // 65536

typedef __attribute__((ext_vector_type(8))) short short8;   // 8 bf16 (4 VGPRs)
typedef __attribute__((ext_vector_type(4))) float f32x4;    // 4 fp32 acc

// bf16 <-> f32 helpers (RNE)
__device__ inline float bf2f(unsigned short u) {
    union { float f; unsigned int i; } v; v.i = ((unsigned int)u) << 16; return v.f;
}
__device__ inline unsigned short f2bf(float f) {
    union { float f; unsigned int i; } v; v.f = f;
    unsigned int r = v.i + 0x7FFFu + ((v.i >> 16) & 1u);
    return (unsigned short)(r >> 16);
}

// async global->LDS, 16 B per lane (wave-uniform LDS base + lane*16)
__device__ __forceinline__ void gl_lds16(const void* g, void* l) {
    __builtin_amdgcn_global_load_lds(
        (const __attribute__((address_space(1))) unsigned int*)g,
        (__attribute__((address_space(3))) unsigned int*)l, 16, 0, 0);
}

#define WAIT_VM(N) asm volatile("s_waitcnt vmcnt(" #N ")" ::: "memory")
#define WAIT_LGKM0() asm volatile("s_waitcnt lgkmcnt(0)" ::: "memory")

// ---------------------------------------------------------------------------
// K0: merged weights (bf16 out).
// ---------------------------------------------------------------------------
__global__ void k_prep(const float* __restrict__ Wx, const float* __restrict__ bx,
                       const float* __restrict__ Wfx, const float* __restrict__ bfx,
                       const float* __restrict__ Wslice, const float* __restrict__ bslice,
                       unsigned short* __restrict__ Wcatb, float* __restrict__ bcat)
{
    int row = blockIdx.x;   // 0..1023
    int t = threadIdx.x;    // 64
    if (row < 512) {
        for (int c = t; c < 256; c += 64) Wcatb[row*256 + c] = f2bf(Wfx[row*256 + c]);
        if (t == 0) bcat[row] = bfx[row];
    } else {
        int r = row - 512, h = r >> 6, s = r & 63;
        for (int c = t; c < 256; c += 64) {
            float acc = 0.f;
            for (int d = 0; d < 64; ++d)
                acc += Wslice[s*64 + d] * Wx[(h*64 + d)*256 + c];
            Wcatb[row*256 + c] = f2bf(acc);
        }
        if (t == 0) {
            float acc = bslice[s];
            for (int d = 0; d < 64; ++d) acc += Wslice[s*64 + d] * bx[h*64 + d];
            bcat[row] = acc;
        }
    }
}

// x (fp32) -> xb (bf16), 8 elems/thread
__global__ void k_xcast(const float* __restrict__ x, unsigned short* __restrict__ xb)
{
    size_t i = ((size_t)blockIdx.x*256 + threadIdx.x)*8;
    float4 a = *(const float4*)(x + i);
    float4 b = *(const float4*)(x + i + 4);
    *(ushort4*)(xb + i)     = make_ushort4(f2bf(a.x), f2bf(a.y), f2bf(a.z), f2bf(a.w));
    *(ushort4*)(xb + i + 4) = make_ushort4(f2bf(b.x), f2bf(b.y), f2bf(b.z), f2bf(b.w));
}

// ---------------------------------------------------------------------------
// K1: MFMA GEMM C[65536 x 1024] = xb @ Wcatb^T + bcat, fused epilogues.
// STORE-COALESCING FIX: both epilogues route through the (dead) K-loop LDS:
// lane-fragment values -> 128x128 bf16 LDS tile (XOR-swizzled, involution on
// both sides -> bit-identical data) -> 16B stores in 256B-contiguous runs.
// Old path emitted 32B-granular HBM scatters (ushort4 @ d*NTOK / u16 stride
// 16) -> effective ~2 TB/s ceiling = the measured 77 us = bytes/2TB/s.
// ---------------------------------------------------------------------------
__global__ __launch_bounds__(512, 4) void k_gemm1(
    const unsigned short* __restrict__ Xb, const unsigned short* __restrict__ Wb,
    const float* __restrict__ bias, const float* __restrict__ temperature,
    unsigned short* __restrict__ fx_t, unsigned short* __restrict__ wbuf)
{
    __shared__ unsigned short SH[4*128*32];   // K-loop dbuf; reused as 128x128 epilogue tile
    unsigned short* EP = SH;
    int bid = blockIdx.x;             // 4096
    int xcd = bid & 7;
    int inner = bid >> 3;             // temporal order within one XCD
    int rt = xcd*64 + (inner >> 3);   // 0..511
    int ct = inner & 7;               // 0..7
    int m0 = rt*128, n0 = ct*128;
    int tid = threadIdx.x;            // 0..511
    int lane = tid & 63, w = tid >> 6;    // 8 waves
    int wrow = w >> 1, wcol = w & 1;      // 4x2 wave grid, wave tile 32x64
    int lr = lane & 15, lq = lane >> 4;
    int lqs = lq ^ ((lr >> 1) & 3);   // swizzled read slot (verified, 0 conflicts)

    f32x4 acc[2][4];
#pragma unroll
    for (int i = 0; i < 2; i++)
#pragma unroll
        for (int j = 0; j < 4; j++) acc[i][j] = (f32x4)(0.f);

    int r0 = tid >> 2;                                  // 0..127
    int kswz = (((tid & 3) ^ ((tid >> 3) & 3))) * 8;    // pre-swizzled source slot

    auto stage = [&](int buf, int k0) {
        gl_lds16(Xb + (size_t)(m0 + r0)*256 + k0 + kswz, &SH[buf*4096 + (size_t)tid*8]);
        gl_lds16(Wb + (size_t)(n0 + r0)*256 + k0 + kswz, &SH[8192 + buf*4096 + (size_t)tid*8]);
    };

    stage(0, 0);
    stage(1, 32);      // 4 vmem ops in flight per wave
    int cur = 0;
#pragma unroll
    for (int t = 0; t < 8; ++t) {
        if (t < 7) { WAIT_VM(2); } else { WAIT_VM(0); }
        __builtin_amdgcn_s_barrier();        // buf[cur] ready for all waves
        short8 af[2], bf[4];
#pragma unroll
        for (int i = 0; i < 2; i++)
            af[i] = *(const short8*)&SH[cur*4096 + (wrow*32 + i*16 + lr)*32 + lqs*8];
#pragma unroll
        for (int j = 0; j < 4; j++)
            bf[j] = *(const short8*)&SH[8192 + cur*4096 + (wcol*64 + j*16 + lr)*32 + lqs*8];
        WAIT_LGKM0();
        __builtin_amdgcn_sched_barrier(0);
        __builtin_amdgcn_s_barrier();        // all waves done reading buf[cur]
        if (t < 6) stage(cur, (t + 2) * 32); // overwrite cur for iter t+2
#pragma unroll
        for (int i = 0; i < 2; i++)
#pragma unroll
            for (int j = 0; j < 4; j++)
                acc[i][j] = __builtin_amdgcn_mfma_f32_16x16x32_bf16(af[i], bf[j], acc[i][j], 0, 0, 0);
        cur ^= 1;
    }

    float bv[4];
#pragma unroll
    for (int j = 0; j < 4; j++) bv[j] = bias[n0 + wcol*64 + j*16 + lr];

    if (n0 < 512) {
        // fx half -> EP transposed [col(d)][tok], slot-swizzled; then coalesced
        // 16B stores: fx_t row = batch*512 + n0 + col, 256B contiguous per row.
#pragma unroll
        for (int i = 0; i < 2; i++) {
            int slot = wrow*8 + i*4 + lq;       // tok>>2
#pragma unroll
            for (int j = 0; j < 4; j++) {
                int col = wcol*64 + j*16 + lr;
                int su = slot ^ (col & 15);
                ushort4 pk = make_ushort4(
                    f2bf(acc[i][j][0] + bv[j]), f2bf(acc[i][j][1] + bv[j]),
                    f2bf(acc[i][j][2] + bv[j]), f2bf(acc[i][j][3] + bv[j]));
                *(ushort4*)&EP[col*128 + su*4] = pk;
            }
        }
        __syncthreads();
        int rowbase = (m0 >> 14)*512 + n0;     // global fx_t row of collocal 0
        int mloc = m0 & (NTOK-1);
#pragma unroll
        for (int p = 0; p < 4; ++p) {
            int unit = p*512 + tid;
            int rowc = unit >> 4, chunk = unit & 15;
            int rx = rowc & 15;
            ushort4 lo = *(const ushort4*)&EP[rowc*128 + ((2*chunk) ^ rx)*4];
            ushort4 hi = *(const ushort4*)&EP[rowc*128 + ((2*chunk + 1) ^ rx)*4];
            ushort4* dst = (ushort4*)(fx_t + (size_t)(rowbase + rowc)*NTOK + mloc + chunk*8);
            dst[0] = lo; dst[1] = hi;
        }
    } else {
        // logits half: softmax (unchanged math) -> EP[tok][col^ (lq<<1)];
        // then coalesced stores, 256B contiguous per token row.
        int h = (n0 - 512 + wcol*64) >> 6;
        float it = 1.f / fmaxf(temperature[h], 1e-4f);
#pragma unroll
        for (int i = 0; i < 2; i++) {
            int tokloc = wrow*32 + i*16 + lq*4;
#pragma unroll
            for (int r = 0; r < 4; r++) {
                float v[4];
#pragma unroll
                for (int j = 0; j < 4; j++) v[j] = (acc[i][j][r] + bv[j]) * it;
                float mx = fmaxf(fmaxf(v[0], v[1]), fmaxf(v[2], v[3]));
                mx = fmaxf(mx, __shfl_xor(mx, 1));
                mx = fmaxf(mx, __shfl_xor(mx, 2));
                mx = fmaxf(mx, __shfl_xor(mx, 4));
                mx = fmaxf(mx, __shfl_xor(mx, 8));
                float e[4], sm = 0.f;
#pragma unroll
                for (int j = 0; j < 4; j++) { e[j] = __expf(v[j] - mx); sm += e[j]; }
                sm += __shfl_xor(sm, 1);
                sm += __shfl_xor(sm, 2);
                sm += __shfl_xor(sm, 4);
                sm += __shfl_xor(sm, 8);
                float inv = 1.f / sm;
                int tk = tokloc + r;
#pragma unroll
                for (int j = 0; j < 4; j++) {
                    int col = wcol*64 + j*16 + lr;
                    EP[tk*128 + (col ^ (lq << 1))] = f2bf(e[j] * inv);
                }
            }
        }
        __syncthreads();
        int colb0 = n0 - 512;
#pragma unroll
        for (int p = 0; p < 4; ++p) {
            int unit = p*512 + tid;
            int tok = unit >> 4, chunk = unit & 15;
            int k = (tok >> 2) & 3;
            uint4 outv;
            outv.x = *(const unsigned*)&EP[tok*128 + chunk*8 + ((0 ^ k) << 1)];
            outv.y = *(const unsigned*)&EP[tok*128 + chunk*8 + ((1 ^ k) << 1)];
            outv.z = *(const unsigned*)&EP[tok*128 + chunk*8 + ((2 ^ k) << 1)];
            outv.w = *(const unsigned*)&EP[tok*128 + chunk*8 + ((3 ^ k) << 1)];
            *(uint4*)&wbuf[(size_t)(m0 + tok)*512 + colb0 + chunk*8] = outv;
        }
    }
}

// ---------------------------------------------------------------------------
// K2: MFMA tok-reduction (R6/R8 verified version). Per (b,h):
// C[64s x 64d] = sum_n w[n][s] fx[n][d]; norm from af registers.
// ---------------------------------------------------------------------------
__global__ __launch_bounds__(256) void k_tok(
    const unsigned short* __restrict__ wbuf, const unsigned short* __restrict__ fx_t,
    float* __restrict__ tok_acc, float* __restrict__ norm_acc)
{
    __shared__ unsigned short As[2][32*64];   // [token][s]  (linear gl_lds16 dest)
    __shared__ unsigned short Bs[2][64*32];   // [d][token slots swizzled]
    int chunk = blockIdx.x;   // 0..31
    int bh = blockIdx.y;      // 0..31
    int b = bh >> 3, h = bh & 7;
    int n0 = chunk * 512;
    int tid = threadIdx.x;
    int lane = tid & 63, w = tid >> 6;
    int lr = lane & 15, lq = lane >> 4;
    int lqs = lq ^ ((lr >> 1) & 3);

    f32x4 acc[4];
#pragma unroll
    for (int j = 0; j < 4; j++) acc[j] = (f32x4)(0.f);
    float nacc = 0.f;

    const unsigned short* wsrc =
        wbuf + ((size_t)(b*NTOK + n0 + (tid >> 3)))*512 + h*64 + (tid & 7)*8;
    int kswz = (((tid & 3) ^ ((tid >> 3) & 3))) * 8;
    const unsigned short* fsrc =
        fx_t + ((size_t)bh*64 + (tid >> 2))*NTOK + n0 + kswz;

    auto stage = [&](int buf, int kk) {
        gl_lds16(wsrc + (size_t)kk*512, &As[buf][(size_t)tid*8]);
        gl_lds16(fsrc + kk,             &Bs[buf][(size_t)tid*8]);
    };

    stage(0, 0);
    stage(1, 32);     // 4 vmem ops in flight per wave
    int cur = 0;
#pragma unroll
    for (int t = 0; t < 16; ++t) {
        if (t < 15) { WAIT_VM(2); } else { WAIT_VM(0); }
        __builtin_amdgcn_s_barrier();
        // af[e] = w[tok = lq*8+e][s = w*16+lr]
        const unsigned short* arow = &As[cur][w*16 + lr];
        short8 af;
#pragma unroll
        for (int e = 0; e < 8; ++e)
            af[e] = (short)arow[(lq*8 + e)*64];
        short8 bfv[4];
#pragma unroll
        for (int j = 0; j < 4; j++)
            bfv[j] = *(const short8*)&Bs[cur][(j*16 + lr)*32 + lqs*8];
        WAIT_LGKM0();
        __builtin_amdgcn_sched_barrier(0);
        __builtin_amdgcn_s_barrier();
        if (t < 14) stage(cur, (t + 2) * 32);

        float ns = 0.f;
#pragma unroll
        for (int e = 0; e < 8; ++e) ns += bf2f((unsigned short)af[e]);
        nacc += ns;
#pragma unroll
        for (int j = 0; j < 4; j++)
            acc[j] = __builtin_amdgcn_mfma_f32_16x16x32_bf16(af, bfv[j], acc[j], 0, 0, 0);
        cur ^= 1;
    }

#pragma unroll
    for (int j = 0; j < 4; j++) {
        int d = j*16 + lr;
#pragma unroll
        for (int r = 0; r < 4; r++) {
            int s = w*16 + lq*4 + r;
            atomicAdd(&tok_acc[((size_t)bh*64 + s)*64 + d], acc[j][r]);
        }
    }
    nacc += __shfl_xor(nacc, 16);
    nacc += __shfl_xor(nacc, 32);
    if (lq == 0)
        atomicAdd(&norm_acc[bh*64 + w*16 + lr], nacc);
}

// K3b: per b: kv = mean_h (tok/(norm+1e-5)); kn = rownorm(kv@Wk^T); v = kv@Wv^T
__global__ __launch_bounds__(256) void k_kv(
    const float* __restrict__ tok, const float* __restrict__ norm,
    const float* __restrict__ Wk, const float* __restrict__ Wv,
    float* __restrict__ kn_out, float* __restrict__ v_out)
{
    __shared__ float KV[64][65];
    __shared__ float TMP[64][65];
    __shared__ float rn[64];
    __shared__ float inv[8][64];
    int b = blockIdx.x, tid = threadIdx.x;
    for (int idx = tid; idx < 512; idx += 256) {
        int h = idx >> 6, s = idx & 63;
        inv[h][s] = 1.f / (norm[(b*8 + h)*64 + s] + 1e-5f);
    }
    __syncthreads();
    for (int idx = tid; idx < 4096; idx += 256) {
        int s = idx >> 6;
        float acc = 0.f;
        for (int h = 0; h < 8; ++h)
            acc += tok[((size_t)(b*8 + h))*4096 + idx] * inv[h][s];
        KV[s][idx & 63] = acc * 0.125f;
    }
    __syncthreads();
    for (int idx = tid; idx < 4096; idx += 256) {
        int s = idx >> 6, d = idx & 63;
        float a = 0.f;
        for (int e = 0; e < 64; ++e) a += KV[s][e] * Wk[d*64 + e];
        TMP[s][d] = a;
    }
    __syncthreads();
    if (tid < 64) {
        float a = 0.f;
        for (int d = 0; d < 64; ++d) { float x = TMP[tid][d]; a += x*x; }
        rn[tid] = fmaxf(sqrtf(a), 1e-12f);
    }
    __syncthreads();
    for (int idx = tid; idx < 4096; idx += 256) {
        int s = idx >> 6, d = idx & 63;
        kn_out[(size_t)b*4096 + idx] = TMP[s][d] / rn[s];
    }
    for (int idx = tid; idx < 4096; idx += 256) {
        int s = idx >> 6, d = idx & 63;
        float a = 0.f;
        for (int e = 0; e < 64; ++e) a += KV[s][e] * Wv[d*64 + e];
        v_out[(size_t)b*4096 + idx] = a;
    }
}

// K3c: per (b,h): tn = tok/(norm+1e-5); q = tn@Wq^T, cosine attn vs kn,
// softmax, @v, + srs*tn
__global__ __launch_bounds__(256) void k_attn(
    const float* __restrict__ tok, const float* __restrict__ norm,
    const float* __restrict__ Wq,
    const float* __restrict__ kn, const float* __restrict__ vbuf,
    const float* __restrict__ attn_scale, const float* __restrict__ srs,
    float* __restrict__ out_tok)
{
    __shared__ float TN[64][65];
    __shared__ float Q[64][65];
    __shared__ float KN[64][65];
    __shared__ float L[64][65];
    __shared__ float rn[64];
    int h = blockIdx.x & 7, b = blockIdx.x >> 3;
    int bh = b*8 + h;
    int tid = threadIdx.x;
    for (int idx = tid; idx < 4096; idx += 256) {
        int g = idx >> 6;
        TN[g][idx & 63] = tok[(size_t)bh*4096 + idx] / (norm[bh*64 + g] + 1e-5f);
        KN[g][idx & 63] = kn[(size_t)b*4096 + idx];
    }
    __syncthreads();
    for (int idx = tid; idx < 4096; idx += 256) {
        int g = idx >> 6, d = idx & 63;
        float a = 0.f;
        for (int e = 0; e < 64; ++e) a += TN[g][e] * Wq[d*64 + e];
        Q[g][d] = a;
    }
    __syncthreads();
    if (tid < 64) {
        float a = 0.f;
        for (int d = 0; d < 64; ++d) { float x = Q[tid][d]; a += x*x; }
        rn[tid] = fmaxf(sqrtf(a), 1e-12f);
    }
    __syncthreads();
    float scale = attn_scale[h];
    for (int idx = tid; idx < 4096; idx += 256) {
        int g = idx >> 6, s = idx & 63;
        float a = 0.f;
        for (int e = 0; e < 64; ++e) a += Q[g][e] * KN[s][e];
        L[g][s] = a / rn[g] * scale;
    }
    __syncthreads();
    if (tid < 64) {
        float mx = -1e30f;
        for (int s = 0; s < 64; ++s) mx = fmaxf(mx, L[tid][s]);
        float sm = 0.f;
        for (int s = 0; s < 64; ++s) { float e = expf(L[tid][s]-mx); L[tid][s] = e; sm += e; }
        float ivv = 1.f/sm;
        for (int s = 0; s < 64; ++s) L[tid][s] *= ivv;
    }
    __syncthreads();
    float srsv = srs[0];
    for (int idx = tid; idx < 4096; idx += 256) {
        int g = idx >> 6, d = idx & 63;
        float a = 0.f;
        for (int s = 0; s < 64; ++s) a += L[g][s] * vbuf[(size_t)b*4096 + s*64 + d];
        out_tok[(size_t)bh*4096 + idx] = a + srsv * TN[g][d];
    }
}

// K3d: MTb[b][j][h*64+s] = sum_d out_tok[b,h,s,d] * Wout[j, h*64+d]  (bf16 out)
__global__ __launch_bounds__(256) void k_mt(
    const float* __restrict__ out_tok, const float* __restrict__ Wout,
    unsigned short* __restrict__ MTb)
{
    __shared__ float Wt[64][68];   // [d][j]
    __shared__ float Ot[64][68];   // [d][s]
    int jt = blockIdx.x, h = blockIdx.y, b = blockIdx.z;
    int j0 = jt * 64;
    int tid = threadIdx.x;
    int tx = tid & 15, ty = tid >> 4;
#pragma unroll
    for (int i = 0; i < 4; i++) {
        int flat = tid + i*256;
        int r = flat >> 4;
        int c4 = (flat & 15) * 4;
        float4 wv = *(const float4*)(Wout + (size_t)(j0+r)*512 + h*64 + c4);
        Wt[c4+0][r]=wv.x; Wt[c4+1][r]=wv.y; Wt[c4+2][r]=wv.z; Wt[c4+3][r]=wv.w;
        float4 ov = *(const float4*)(out_tok + ((size_t)(b*8+h)*64 + r)*64 + c4);
        Ot[c4+0][r]=ov.x; Ot[c4+1][r]=ov.y; Ot[c4+2][r]=ov.z; Ot[c4+3][r]=ov.w;
    }
    __syncthreads();
    float acc[4][4] = {{0.f}};
#pragma unroll 8
    for (int d = 0; d < 64; ++d) {
        float av[4], bv[4];
        *(float4*)av = *(const float4*)&Wt[d][ty*4];
        *(float4*)bv = *(const float4*)&Ot[d][tx*4];
#pragma unroll
        for (int i = 0; i < 4; i++)
#pragma unroll
            for (int j = 0; j < 4; j++) acc[i][j] += av[i]*bv[j];
    }
#pragma unroll
    for (int i = 0; i < 4; i++) {
        int j = j0 + ty*4 + i;
#pragma unroll
        for (int jj = 0; jj < 4; jj++) {
            int s = tx*4 + jj;
            MTb[((size_t)(b*256) + j)*512 + h*64 + s] = f2bf(acc[i][jj]);
        }
    }
}

// ---------------------------------------------------------------------------
// K5: MFMA GEMM. out[65536 x 256] = wbuf(bf16) @ MTb[b]^T + bout (fp32 out)
// Same store-coalescing fix: C staged in LDS (two 64-row halves), then
// float4 stores in 512B-contiguous runs per row.
// ---------------------------------------------------------------------------
__global__ __launch_bounds__(512, 4) void k_gemm2(
    const unsigned short* __restrict__ A, const unsigned short* __restrict__ Ball,
    const float* __restrict__ bias, float* __restrict__ C)
{
    __shared__ unsigned short SH[4*128*32];   // K-loop dbuf; reused as 64x128 f32 tile
    float* EPf = (float*)SH;
    int bid = blockIdx.x;             // 1024
    int xcd = bid & 7;
    int inner = bid >> 3;             // 0..127
    int rt = xcd*64 + (inner >> 1);   // 0..511
    int ct = inner & 1;
    int m0 = rt*128, n0 = ct*128;
    const unsigned short* Bm = Ball + (size_t)(m0 >> 14) * 256 * 512;
    int tid = threadIdx.x;            // 0..511
    int lane = tid & 63, w = tid >> 6;
    int wrow = w >> 1, wcol = w & 1;
    int lr = lane & 15, lq = lane >> 4;
    int lqs = lq ^ ((lr >> 1) & 3);

    f32x4 acc[2][4];
#pragma unroll
    for (int i = 0; i < 2; i++)
#pragma unroll
        for (int j = 0; j < 4; j++) acc[i][j] = (f32x4)(0.f);

    int r0 = tid >> 2;
    int kswz = (((tid & 3) ^ ((tid >> 3) & 3))) * 8;

    auto stage = [&](int buf, int k0) {
        gl_lds16(A + (size_t)(m0 + r0)*512 + k0 + kswz,  &SH[buf*4096 + (size_t)tid*8]);
        gl_lds16(Bm + (size_t)(n0 + r0)*512 + k0 + kswz, &SH[8192 + buf*4096 + (size_t)tid*8]);
    };

    stage(0, 0);
    stage(1, 32);
    int cur = 0;
#pragma unroll
    for (int t = 0; t < 16; ++t) {
        if (t < 15) { WAIT_VM(2); } else { WAIT_VM(0); }
        __builtin_amdgcn_s_barrier();
        short8 af[2], bf[4];
#pragma unroll
        for (int i = 0; i < 2; i++)
            af[i] = *(const short8*)&SH[cur*4096 + (wrow*32 + i*16 + lr)*32 + lqs*8];
#pragma unroll
        for (int j = 0; j < 4; j++)
            bf[j] = *(const short8*)&SH[8192 + cur*4096 + (wcol*64 + j*16 + lr)*32 + lqs*8];
        WAIT_LGKM0();
        __builtin_amdgcn_sched_barrier(0);
        __builtin_amdgcn_s_barrier();
        if (t < 14) stage(cur, (t + 2) * 32);
#pragma unroll
        for (int i = 0; i < 2; i++)
#pragma unroll
            for (int j = 0; j < 4; j++)
                acc[i][j] = __builtin_amdgcn_mfma_f32_16x16x32_bf16(af[i], bf[j], acc[i][j], 0, 0, 0);
        cur ^= 1;
    }

    float bv[4];
#pragma unroll
    for (int j = 0; j < 4; j++) bv[j] = bias[n0 + wcol*64 + j*16 + lr];

#pragma unroll
    for (int half = 0; half < 2; ++half) {
        __syncthreads();
        if ((wrow >> 1) == half) {
#pragma unroll
            for (int j = 0; j < 4; j++) {
                int col = wcol*64 + j*16 + lr;
                int csw = col ^ (lq << 4);
#pragma unroll
                for (int i = 0; i < 2; i++) {
                    int row = (wrow & 1)*32 + i*16 + lq*4;
#pragma unroll
                    for (int r = 0; r < 4; r++)
                        EPf[(row + r)*128 + csw] = acc[i][j][r] + bv[j];
                }
            }
        }
        __syncthreads();
        int mbase = m0 + half*64;
#pragma unroll
        for (int p = 0; p < 4; ++p) {
            int unit = p*512 + tid;
            int rowc = unit >> 5, chunk = unit & 31;
            int k = (rowc >> 2) & 3;
            float4 v = *(const float4*)&EPf[rowc*128 + ((chunk ^ (k << 2)) << 2)];
            *(float4*)&C[(size_t)(mbase + rowc)*256 + n0 + chunk*4] = v;
        }
    }
}

// ---------------------------------------------------------------------------
extern "C" void kernel_launch(void* const* d_in, const int* in_sizes, int n_in,
                              void* d_out, int out_size, void* d_ws, size_t ws_size,
                              hipStream_t stream)
{
    const float* x      = (const float*)d_in[0];
    const float* Wx     = (const float*)d_in[1];
    const float* bx     = (const float*)d_in[2];
    const float* Wfx    = (const float*)d_in[3];
    const float* bfx    = (const float*)d_in[4];
    const float* Wslice = (const float*)d_in[5];
    const float* bslice = (const float*)d_in[6];
    const float* temperature = (const float*)d_in[7];
    const float* Wq     = (const float*)d_in[8];
    const float* Wk     = (const float*)d_in[9];
    const float* Wv     = (const float*)d_in[10];
    const float* attn_scale = (const float*)d_in[11];
    const float* srs    = (const float*)d_in[12];
    const float* Wout   = (const float*)d_in[13];
    const float* bout   = (const float*)d_in[14];
    float* out = (float*)d_out;
    float* ws  = (float*)d_ws;

    // workspace layout (float offsets)
    float* tok  = ws + 0;          // 131072
    float* norm = ws + 131072;     // 2048
    float* bcat = ws + 133120;     // 1024
    float* kn   = ws + 134144;     // 16384
    float* vb   = ws + 150528;     // 16384
    float* ot   = ws + 166912;     // 131072
    unsigned short* Wcatb = (unsigned short*)(ws + 297984);  // 1024*256  -> 131072 floats
    unsigned short* MTb   = (unsigned short*)(ws + 429056);  // 4*256*512 -> 262144 floats
    unsigned short* xb    = (unsigned short*)(ws + 691200);  // 65536*256 -> 8388608 floats
    unsigned short* wbuf  = (unsigned short*)(ws + 9079808); // 65536*512 -> 16777216 floats
    unsigned short* fx_t  = (unsigned short*)d_out;          // 64 MiB scratch, consumed by k_tok

    hipMemsetAsync(tok, 0, 133120 * sizeof(float), stream);  // tok_acc + norm
    k_prep<<<1024, 64, 0, stream>>>(Wx, bx, Wfx, bfx, Wslice, bslice, Wcatb, bcat);
    k_xcast<<<8192, 256, 0, stream>>>(x, xb);
    k_gemm1<<<4096, 512, 0, stream>>>(xb, Wcatb, bcat, temperature, fx_t, wbuf);
    k_tok<<<dim3(32, 32), 256, 0, stream>>>(wbuf, fx_t, tok, norm);
    k_kv<<<4, 256, 0, stream>>>(tok, norm, Wk, Wv, kn, vb);
    k_attn<<<32, 256, 0, stream>>>(tok, norm, Wq, kn, vb, attn_scale, srs, ot);
    k_mt<<<dim3(4, 8, 4), 256, 0, stream>>>(ot, Wout, MTb);
    k_gemm2<<<1024, 512, 0, stream>>>(wbuf, MTb, bout, out);
}